// Round 2
// baseline (178.900 us; speedup 1.0000x reference)
//
#include <hip/hip_runtime.h>

#define DIOU_EPS 1e-7f

constexpr int BLOCK = 256;
constexpr int ITEMS = 4;                 // elements per thread
constexpr int CHUNK = BLOCK * ITEMS;     // 1024 elements per block

__global__ void zero_out_kernel(float* out) {
    out[0] = 0.0f;
}

__device__ __forceinline__ float diou_elem(float4 a, float4 b, int m) {
    // areas
    float a1 = (a.z - a.x) * (a.w - a.y);
    float a2 = (b.z - b.x) * (b.w - b.y);

    // intersection
    float iw = fmaxf(fminf(a.z, b.z) - fmaxf(a.x, b.x), 0.0f);
    float ih = fmaxf(fminf(a.w, b.w) - fmaxf(a.y, b.y), 0.0f);
    float inter = iw * ih;
    float uni = a1 + a2 - inter;
    float iou = inter / uni;

    // enclosing box
    float wc = fmaxf(a.z, b.z) - fminf(a.x, b.x);
    float hc = fmaxf(a.w, b.w) - fminf(a.y, b.y);
    float area_c = wc * hc;

    float giou = iou - (area_c - uni) / area_c;

    // center distance / diagonal
    float dx = (a.x + a.z - b.x - b.z) * 0.5f;
    float dy = (a.y + a.w - b.y - b.w) * 0.5f;
    float d2 = dx * dx + dy * dy;
    float diag2 = wc * wc + hc * hc;

    float diou = giou - d2 / (diag2 + DIOU_EPS);
    float mf = (float)(m != 0);
    return mf * (1.0f - diou);
}

__global__ __launch_bounds__(BLOCK) void diou_loss_kernel(
    const float4* __restrict__ boxes1,
    const float4* __restrict__ boxes2,
    const int* __restrict__ mask,
    const int* __restrict__ num_boxes,
    float* __restrict__ out,
    int n)
{
    const int t = threadIdx.x;
    const int base = blockIdx.x * CHUNK;

    float acc = 0.0f;

    if (base + CHUNK <= n) {
        // fast path: all 12 load instructions independent, issued before compute.
        // index pattern j*BLOCK + t keeps every instruction stride-1 coalesced.
        float4 A[ITEMS], B[ITEMS];
        int    M[ITEMS];
        #pragma unroll
        for (int j = 0; j < ITEMS; ++j) A[j] = boxes1[base + j * BLOCK + t];
        #pragma unroll
        for (int j = 0; j < ITEMS; ++j) B[j] = boxes2[base + j * BLOCK + t];
        #pragma unroll
        for (int j = 0; j < ITEMS; ++j) M[j] = mask[base + j * BLOCK + t];

        #pragma unroll
        for (int j = 0; j < ITEMS; ++j) acc += diou_elem(A[j], B[j], M[j]);
    } else {
        #pragma unroll
        for (int j = 0; j < ITEMS; ++j) {
            int i = base + j * BLOCK + t;
            if (i < n) acc += diou_elem(boxes1[i], boxes2[i], mask[i]);
        }
    }

    // wave-64 butterfly reduce
    #pragma unroll
    for (int off = 32; off > 0; off >>= 1)
        acc += __shfl_down(acc, off, 64);

    __shared__ float wave_sums[BLOCK / 64];
    int wave = t >> 6;
    if ((t & 63) == 0) wave_sums[wave] = acc;
    __syncthreads();

    if (t == 0) {
        float s = wave_sums[0] + wave_sums[1] + wave_sums[2] + wave_sums[3];
        float inv_nb = 1.0f / (float)num_boxes[0];
        atomicAdd(out, s * inv_nb);
    }
}

extern "C" void kernel_launch(void* const* d_in, const int* in_sizes, int n_in,
                              void* d_out, int out_size, void* d_ws, size_t ws_size,
                              hipStream_t stream) {
    const float4* boxes1 = (const float4*)d_in[0];   // (B,Q,4) f32
    const float4* boxes2 = (const float4*)d_in[1];   // (B,Q,4) f32
    const int* mask = (const int*)d_in[2];           // (B,Q) bool -> int32
    const int* num_boxes = (const int*)d_in[3];      // scalar

    float* out = (float*)d_out;
    int n = in_sizes[2];                             // B*Q pairs

    zero_out_kernel<<<1, 1, 0, stream>>>(out);

    int grid = (n + CHUNK - 1) / CHUNK;              // 4096 for n = 4,194,304
    diou_loss_kernel<<<grid, BLOCK, 0, stream>>>(boxes1, boxes2, mask, num_boxes, out, n);
}

// Round 3
// 164.093 us; speedup vs baseline: 1.0902x; 1.0902x over previous
//
#include <hip/hip_runtime.h>

#define DIOU_EPS 1e-7f

constexpr int BLOCK = 256;
constexpr int ITEMS = 8;                 // elements per thread
constexpr int CHUNK = BLOCK * ITEMS;     // 2048 elements per block

__global__ void zero_out_kernel(float* out) {
    out[0] = 0.0f;
}

__device__ __forceinline__ float rcp_fast(float x) {
    return __builtin_amdgcn_rcpf(x);     // v_rcp_f32, ~1 ulp; threshold 3.8e-2 abs -> safe
}

__device__ __forceinline__ float diou_elem(float4 a, float4 b, int m) {
    // areas
    float a1 = (a.z - a.x) * (a.w - a.y);
    float a2 = (b.z - b.x) * (b.w - b.y);

    // intersection
    float iw = fmaxf(fminf(a.z, b.z) - fmaxf(a.x, b.x), 0.0f);
    float ih = fmaxf(fminf(a.w, b.w) - fmaxf(a.y, b.y), 0.0f);
    float inter = iw * ih;
    float uni = a1 + a2 - inter;

    // enclosing box
    float wc = fmaxf(a.z, b.z) - fminf(a.x, b.x);
    float hc = fmaxf(a.w, b.w) - fminf(a.y, b.y);
    float area_c = wc * hc;

    // center distance / diagonal
    float dx = (a.x + a.z - b.x - b.z) * 0.5f;
    float dy = (a.y + a.w - b.y - b.w) * 0.5f;
    float d2 = dx * dx + dy * dy;
    float diag2 = wc * wc + hc * hc;

    // loss = 1 - diou = 2 - iou - uni/area_c + d2/(diag2+eps)
    float iou_term  = inter * rcp_fast(uni);
    float giou_term = uni * rcp_fast(area_c);
    float pen_term  = d2 * rcp_fast(diag2 + DIOU_EPS);
    float loss = 2.0f - iou_term - giou_term + pen_term;

    float mf = (m != 0) ? 1.0f : 0.0f;
    return mf * loss;
}

__global__ __launch_bounds__(BLOCK) void diou_loss_kernel(
    const float4* __restrict__ boxes1,
    const float4* __restrict__ boxes2,
    const int* __restrict__ mask,
    const int* __restrict__ num_boxes,
    float* __restrict__ out,
    int n)
{
    const int t = threadIdx.x;
    const int base = blockIdx.x * CHUNK;

    float acc = 0.0f;

    if (base + CHUNK <= n) {
        // Issue ALL 24 load instructions (8x dwordx4 A, 8x dwordx4 B, 8x dword M)
        // before any compute; sched_barrier(0) forbids the compiler from sinking
        // loads past it, forcing ~18KB in flight per wave.
        float4 A[ITEMS], B[ITEMS];
        int    M[ITEMS];
        #pragma unroll
        for (int j = 0; j < ITEMS; ++j) A[j] = boxes1[base + j * BLOCK + t];
        #pragma unroll
        for (int j = 0; j < ITEMS; ++j) B[j] = boxes2[base + j * BLOCK + t];
        #pragma unroll
        for (int j = 0; j < ITEMS; ++j) M[j] = mask[base + j * BLOCK + t];

        __builtin_amdgcn_sched_barrier(0);

        #pragma unroll
        for (int j = 0; j < ITEMS; ++j) acc += diou_elem(A[j], B[j], M[j]);
    } else {
        for (int j = 0; j < ITEMS; ++j) {
            int i = base + j * BLOCK + t;
            if (i < n) acc += diou_elem(boxes1[i], boxes2[i], mask[i]);
        }
    }

    // wave-64 reduce
    #pragma unroll
    for (int off = 32; off > 0; off >>= 1)
        acc += __shfl_down(acc, off, 64);

    __shared__ float wave_sums[BLOCK / 64];
    int wave = t >> 6;
    if ((t & 63) == 0) wave_sums[wave] = acc;
    __syncthreads();

    if (t == 0) {
        float s = wave_sums[0] + wave_sums[1] + wave_sums[2] + wave_sums[3];
        float inv_nb = 1.0f / (float)num_boxes[0];
        atomicAdd(out, s * inv_nb);
    }
}

extern "C" void kernel_launch(void* const* d_in, const int* in_sizes, int n_in,
                              void* d_out, int out_size, void* d_ws, size_t ws_size,
                              hipStream_t stream) {
    const float4* boxes1 = (const float4*)d_in[0];   // (B,Q,4) f32
    const float4* boxes2 = (const float4*)d_in[1];   // (B,Q,4) f32
    const int* mask = (const int*)d_in[2];           // (B,Q) bool -> int32
    const int* num_boxes = (const int*)d_in[3];      // scalar

    float* out = (float*)d_out;
    int n = in_sizes[2];                             // B*Q pairs

    zero_out_kernel<<<1, 1, 0, stream>>>(out);

    int grid = (n + CHUNK - 1) / CHUNK;              // 2048 for n = 4,194,304
    diou_loss_kernel<<<grid, BLOCK, 0, stream>>>(boxes1, boxes2, mask, num_boxes, out, n);
}